// Round 13
// baseline (293.881 us; speedup 1.0000x reference)
//
#include <hip/hip_runtime.h>
#include <hip/hip_fp16.h>

#define NEG_SLOPE 0.2f

// -------- edge helpers: edge_index is [2,E] int32 row-major; self-loops appended --------
__device__ __forceinline__ void edge_sd(const int* ei, int E, int e, int& s, int& d) {
    if (e < E) { s = ei[e]; d = ei[E + e]; }
    else       { int v = e - E; s = v; d = v; }
}

__global__ void zero_kernel(int* p, int n) {
    int i = blockIdx.x * blockDim.x + threadIdx.x;
    if (i < n) p[i] = 0;
}

__global__ void deg_kernel(const int* ei, int E, int N, int* deg) {
    int e = blockIdx.x * blockDim.x + threadIdx.x;
    if (e >= E + N) return;
    int s, d; edge_sd(ei, E, e, s, d);
    atomicAdd(&deg[d], 1);
}

// single-block exclusive scan of deg[0..n) -> offsets[0..n], offsets[n] = total
__global__ void scan_kernel(const int* deg, int* offsets, int n) {
    __shared__ int part[1024];
    int t = threadIdx.x;
    int chunk = (n + 1023) / 1024;
    int beg = t * chunk;
    int s = 0;
    for (int i = 0; i < chunk; ++i) {
        int idx = beg + i;
        if (idx < n) s += deg[idx];
    }
    part[t] = s;
    __syncthreads();
    for (int off = 1; off < 1024; off <<= 1) {
        int v = (t >= off) ? part[t - off] : 0;
        __syncthreads();
        part[t] += v;
        __syncthreads();
    }
    if (t == 1023) offsets[n] = part[1023];
    int run = (t == 0) ? 0 : part[t - 1];
    for (int i = 0; i < chunk; ++i) {
        int idx = beg + i;
        if (idx < n) { offsets[idx] = run; run += deg[idx]; }
    }
}

__global__ void fill_kernel(const int* ei, int E, int N, const int* offsets,
                            int* cursor, int* csr_src) {
    int e = blockIdx.x * blockDim.x + threadIdx.x;
    if (e >= E + N) return;
    int s, d; edge_sd(ei, E, e, s, d);
    int pos = offsets[d] + atomicAdd(&cursor[d], 1);
    csr_src[pos] = s;
}

// Fused: xl1 = x@W1 (per node, 512 outputs, stored fp16 for the gather path)
// + es1/ed1 attention scores (computed in f32). Block = 256 thr; wave = head.
__global__ void xw1_attn(const float* __restrict__ x, const float* __restrict__ W1,
                         const float* __restrict__ a_src, const float* __restrict__ a_dst,
                         __half2* __restrict__ xlh, float* __restrict__ es, float* __restrict__ ed,
                         int n) {
    int node = blockIdx.x;
    int t = threadIdx.x;
    __shared__ float xs[6];
    if (t < 6) xs[t] = x[node * 6 + t];
    __syncthreads();
    int j0 = 2 * t, j1 = 2 * t + 1;
    float v0 = 0.f, v1 = 0.f;
#pragma unroll
    for (int k = 0; k < 6; ++k) {
        v0 += xs[k] * W1[k * 512 + j0];
        v1 += xs[k] * W1[k * 512 + j1];
    }
    xlh[(size_t)node * 256 + t] = __floats2half2_rn(v0, v1);
    float ps = v0 * a_src[j0] + v1 * a_src[j1];
    float pd = v0 * a_dst[j0] + v1 * a_dst[j1];
#pragma unroll
    for (int off = 32; off; off >>= 1) {
        ps += __shfl_xor(ps, off);
        pd += __shfl_xor(pd, off);
    }
    int h = t >> 6, lane = t & 63;
    if (lane == 0) { es[node * 4 + h] = ps; ed[node * 4 + h] = pd; }
}

// Softmax weights, all H heads per wave. Wave per node (4 nodes / 256-thr block).
// Lane-parallel over edges: 1 es gather (float4 for H=4) per edge, exp WITHOUT max-shift
// (|e| <= ~3 by construction). Writes unnormalized alpha[i][H] + dinv[n][H] = 1/sum.
template <int H>
__global__ void alpha_kernel(const float* __restrict__ es, const float* __restrict__ ed,
                             const int* __restrict__ offsets, const int* __restrict__ csr_src,
                             float* __restrict__ alpha, float* __restrict__ dinv, int n) {
    int wave = threadIdx.x >> 6, lane = threadIdx.x & 63;
    int node = blockIdx.x * 4 + wave;
    if (node >= n) return;
    int beg = offsets[node], end = offsets[node + 1];
    float edv[H];
#pragma unroll
    for (int h = 0; h < H; ++h) edv[h] = ed[node * H + h];
    float sum[H];
#pragma unroll
    for (int h = 0; h < H; ++h) sum[h] = 0.f;
    for (int chunk = beg; chunk < end; chunk += 64) {
        int i = chunk + lane;
        bool valid = i < end;
        int s = valid ? csr_src[i] : 0;
        if (H == 4) {
            float4 e4 = valid ? *(const float4*)(es + (size_t)s * 4)
                              : make_float4(0.f, 0.f, 0.f, 0.f);
            float ev[4] = {e4.x, e4.y, e4.z, e4.w};
            float a[4];
#pragma unroll
            for (int h = 0; h < 4; ++h) {
                float w = ev[h] + edv[h];
                w = (w > 0.f) ? w : NEG_SLOPE * w;
                a[h] = valid ? __expf(w) : 0.f;
                sum[h] += a[h];
            }
            if (valid)
                *(float4*)(alpha + (size_t)i * 4) = make_float4(a[0], a[1], a[2], a[3]);
        } else {
            float w = (valid ? es[s] : 0.f) + edv[0];
            w = (w > 0.f) ? w : NEG_SLOPE * w;
            float a = valid ? __expf(w) : 0.f;
            sum[0] += a;
            if (valid) alpha[i] = a;
        }
    }
#pragma unroll
    for (int h = 0; h < H; ++h) {
        float s2 = sum[h];
#pragma unroll
        for (int off = 32; off; off >>= 1) s2 += __shfl_xor(s2, off);
        if (lane == 0) dinv[node * H + h] = 1.f / s2;
    }
}

// GAT1 aggregation, ALL 4 HEADS per wave (wave = node, 4 nodes / 256-thr block).
// Lane l covers channels 8l..8l+7 of the full 512-ch row => each edge is ONE 1KB
// fully-contiguous wave gather (170K fat requests vs 680K quarter-row requests).
// 8 gathers in flight. Output hbuf is stored in a lane-structured PERMUTED layout
// via two fully-contiguous 1KB wave stores (per-instruction contiguity, round-11
// lesson): position p<256 holds ch 8*(p/4)+(p&3); p>=256 holds ch 8*((p-256)/4)+4+(p&3).
// xw2_attn compensates in its W2 row indexing.
__global__ void agg4_kernel(const __half* __restrict__ xlh, const float* __restrict__ alpha,
                            const float* __restrict__ dinv, const int* __restrict__ offsets,
                            const int* __restrict__ csr_src, const float* __restrict__ bias,
                            float* __restrict__ out, int n) {
    __shared__ int   s_src[4 * 64];
    __shared__ float s_al [4 * 64 * 4];
    int t = threadIdx.x, wave = t >> 6, lane = t & 63;
    int node = blockIdx.x * 4 + wave;
    int beg = offsets[node], end = offsets[node + 1];
    int woff = wave * 64;
    int hsel = lane >> 4;                 // head of channels 8l..8l+7
    float acc[8] = {0.f, 0.f, 0.f, 0.f, 0.f, 0.f, 0.f, 0.f};

    auto accum = [&](float4 r, float a) {
        const __half2* hp = (const __half2*)&r;
        float2 f0 = __half22float2(hp[0]), f1 = __half22float2(hp[1]);
        float2 f2 = __half22float2(hp[2]), f3 = __half22float2(hp[3]);
        acc[0] += a * f0.x; acc[1] += a * f0.y;
        acc[2] += a * f1.x; acc[3] += a * f1.y;
        acc[4] += a * f2.x; acc[5] += a * f2.y;
        acc[6] += a * f3.x; acc[7] += a * f3.y;
    };

    for (int chunk = beg; chunk < end; chunk += 64) {
        int i = chunk + lane;
        bool valid = i < end;
        s_src[woff + lane] = valid ? csr_src[i] : 0;
        float4 av = valid ? *(const float4*)(alpha + (size_t)i * 4)
                          : make_float4(0.f, 0.f, 0.f, 0.f);
        *(float4*)&s_al[(woff + lane) * 4] = av;
        int cnt = end - chunk; if (cnt > 64) cnt = 64;
        int base = 0;
        for (; base + 8 <= cnt; base += 8) {
            int s0 = s_src[woff+base+0], s1 = s_src[woff+base+1];
            int s2 = s_src[woff+base+2], s3 = s_src[woff+base+3];
            int s4 = s_src[woff+base+4], s5 = s_src[woff+base+5];
            int s6 = s_src[woff+base+6], s7 = s_src[woff+base+7];
            float a0 = s_al[(woff+base+0)*4 + hsel], a1 = s_al[(woff+base+1)*4 + hsel];
            float a2 = s_al[(woff+base+2)*4 + hsel], a3 = s_al[(woff+base+3)*4 + hsel];
            float a4 = s_al[(woff+base+4)*4 + hsel], a5 = s_al[(woff+base+5)*4 + hsel];
            float a6 = s_al[(woff+base+6)*4 + hsel], a7 = s_al[(woff+base+7)*4 + hsel];
            float4 r0 = *(const float4*)(xlh + (size_t)s0 * 512 + lane * 8);
            float4 r1 = *(const float4*)(xlh + (size_t)s1 * 512 + lane * 8);
            float4 r2 = *(const float4*)(xlh + (size_t)s2 * 512 + lane * 8);
            float4 r3 = *(const float4*)(xlh + (size_t)s3 * 512 + lane * 8);
            float4 r4 = *(const float4*)(xlh + (size_t)s4 * 512 + lane * 8);
            float4 r5 = *(const float4*)(xlh + (size_t)s5 * 512 + lane * 8);
            float4 r6 = *(const float4*)(xlh + (size_t)s6 * 512 + lane * 8);
            float4 r7 = *(const float4*)(xlh + (size_t)s7 * 512 + lane * 8);
            accum(r0, a0); accum(r1, a1); accum(r2, a2); accum(r3, a3);
            accum(r4, a4); accum(r5, a5); accum(r6, a6); accum(r7, a7);
        }
        for (; base < cnt; ++base) {
            int   sv = s_src[woff + base];
            float av1 = s_al[(woff + base) * 4 + hsel];
            float4 r = *(const float4*)(xlh + (size_t)sv * 512 + lane * 8);
            accum(r, av1);
        }
    }
    float inv = dinv[node * 4 + hsel];
    int c0 = lane * 8;                    // channels c0..c0+7
    float o[8];
#pragma unroll
    for (int k = 0; k < 8; ++k) o[k] = fmaxf(acc[k] * inv + bias[c0 + k], 0.f);
    // two fully-contiguous 1KB wave stores (permuted layout)
    float* ob = out + (size_t)node * 512;
    *(float4*)(ob + 4 * lane)       = make_float4(o[0], o[1], o[2], o[3]);
    *(float4*)(ob + 256 + 4 * lane) = make_float4(o[4], o[5], o[6], o[7]);
}

// GAT2 weighted gather (H=1), wide-load: 16 lanes x 16B per 256B row => 4 edges per
// instruction; LDS redistribute epilogue for contiguous float2 stores + pool.
__global__ void agg1_kernel(const __half* __restrict__ xlh, const float* __restrict__ alpha,
                            const float* __restrict__ dinv, const int* __restrict__ offsets,
                            const int* __restrict__ csr_src, const float* __restrict__ bias,
                            const int* __restrict__ batch,
                            float* __restrict__ gsum, float* __restrict__ gcnt, int n) {
    __shared__ int   s_src[4 * 64];
    __shared__ float s_al [4 * 64];
    __shared__ float s_red[4][64][8];
    int t = threadIdx.x, wave = t >> 6, lane = t & 63;
    int node = blockIdx.x * 4 + wave;
    int beg = offsets[node], end = offsets[node + 1];
    int woff = wave * 64;
    int lg = lane >> 4;    // edge slot within a 4-edge group
    int lc = lane & 15;    // 16B chunk within the 256B row
    float acc[8] = {0.f, 0.f, 0.f, 0.f, 0.f, 0.f, 0.f, 0.f};

    auto accum = [&](float4 r, float a) {
        const __half2* hp = (const __half2*)&r;
        float2 f0 = __half22float2(hp[0]), f1 = __half22float2(hp[1]);
        float2 f2 = __half22float2(hp[2]), f3 = __half22float2(hp[3]);
        acc[0] += a * f0.x; acc[1] += a * f0.y;
        acc[2] += a * f1.x; acc[3] += a * f1.y;
        acc[4] += a * f2.x; acc[5] += a * f2.y;
        acc[6] += a * f3.x; acc[7] += a * f3.y;
    };

    for (int chunk = beg; chunk < end; chunk += 64) {
        int i = chunk + lane;
        bool valid = i < end;
        s_src[woff + lane] = valid ? csr_src[i] : 0;
        s_al [woff + lane] = valid ? alpha[i] : 0.f;
        int cnt = end - chunk; if (cnt > 64) cnt = 64;
        int base = 0;
        for (; base + 16 <= cnt; base += 16) {
            int e0 = base + lg, e1 = base + 4 + lg, e2 = base + 8 + lg, e3 = base + 12 + lg;
            int   s0 = s_src[woff + e0], s1 = s_src[woff + e1];
            int   s2 = s_src[woff + e2], s3 = s_src[woff + e3];
            float a0 = s_al[woff + e0], a1 = s_al[woff + e1];
            float a2 = s_al[woff + e2], a3 = s_al[woff + e3];
            float4 r0 = *(const float4*)(xlh + (size_t)s0 * 128 + lc * 8);
            float4 r1 = *(const float4*)(xlh + (size_t)s1 * 128 + lc * 8);
            float4 r2 = *(const float4*)(xlh + (size_t)s2 * 128 + lc * 8);
            float4 r3 = *(const float4*)(xlh + (size_t)s3 * 128 + lc * 8);
            accum(r0, a0); accum(r1, a1); accum(r2, a2); accum(r3, a3);
        }
        for (; base < cnt; base += 4) {
            int eg = base + lg;
            bool v = eg < cnt;
            int   sv = v ? s_src[woff + eg] : 0;
            float av = v ? s_al[woff + eg] : 0.f;
            float4 r = *(const float4*)(xlh + (size_t)sv * 128 + lc * 8);
            accum(r, av);
        }
    }
    float4* dst = (float4*)&s_red[wave][lane][0];
    dst[0] = make_float4(acc[0], acc[1], acc[2], acc[3]);
    dst[1] = make_float4(acc[4], acc[5], acc[6], acc[7]);
    int lcs = lane >> 2;
    int pe  = lane & 3;
    float vx = 0.f, vy = 0.f;
#pragma unroll
    for (int g = 0; g < 4; ++g) {
        float2 p = ((float2*)&s_red[wave][g * 16 + lcs][0])[pe];
        vx += p.x; vy += p.y;
    }
    float inv = dinv[node];
    int j0 = 2 * lane;
    float o0 = fmaxf(vx * inv + bias[j0], 0.f);
    float o1 = fmaxf(vy * inv + bias[j0 + 1], 0.f);
    int b = batch[node];
    atomicAdd(&gsum[b * 128 + j0], o0);
    atomicAdd(&gsum[b * 128 + j0 + 1], o1);
    if (lane == 0) atomicAdd(&gcnt[b], 1.f);
}

// xl2 = h @ W2 : [N,512]@[512,128] (stored fp16), fused with GAT2 attention scores.
// h (hbuf) is in agg4's permuted layout: position p<256 -> ch 2p'(=8*(p/4)+(p&3));
// p>=256 -> ch 8*((p-256)/4)+4+((p-256)&3). Compensated via W2 row indexing below.
// 512 threads, 16 nodes/block (625 blocks). Thread t: col j=t&127, rg=t>>7 -> 4 nodes.
__global__ void __launch_bounds__(512)
xw2_attn(const float* __restrict__ h, const float* __restrict__ W2,
         const float* __restrict__ a_src2, const float* __restrict__ a_dst2,
         __half* __restrict__ xl2h, float* __restrict__ es2, float* __restrict__ ed2, int n) {
    __shared__ float hs[16][512];
    __shared__ float red[8][4][2];
    int t = threadIdx.x;
    int n0 = blockIdx.x * 16;
    const float4* hsrc = (const float4*)(h + (size_t)n0 * 512);
    float4* hdst = (float4*)&hs[0][0];
#pragma unroll
    for (int i = 0; i < 4; ++i) hdst[t + 512 * i] = hsrc[t + 512 * i];
    __syncthreads();
    int j = t & 127, rg = t >> 7;
    float acc[4] = {0.f, 0.f, 0.f, 0.f};
    // first half: positions k..k+3 hold channels 2k..2k+3
    for (int k = 0; k < 256; k += 4) {
        int rb = 2 * k;
        float w0 = W2[(rb + 0) * 128 + j];
        float w1 = W2[(rb + 1) * 128 + j];
        float w2 = W2[(rb + 2) * 128 + j];
        float w3 = W2[(rb + 3) * 128 + j];
#pragma unroll
        for (int r = 0; r < 4; ++r) {
            float4 hv = *(const float4*)&hs[rg * 4 + r][k];
            acc[r] += hv.x * w0 + hv.y * w1 + hv.z * w2 + hv.w * w3;
        }
    }
    // second half: positions 256+q..+3 hold channels 2q+4..2q+7
    for (int k = 256; k < 512; k += 4) {
        int rb = 2 * (k - 256) + 4;
        float w0 = W2[(rb + 0) * 128 + j];
        float w1 = W2[(rb + 1) * 128 + j];
        float w2 = W2[(rb + 2) * 128 + j];
        float w3 = W2[(rb + 3) * 128 + j];
#pragma unroll
        for (int r = 0; r < 4; ++r) {
            float4 hv = *(const float4*)&hs[rg * 4 + r][k];
            acc[r] += hv.x * w0 + hv.y * w1 + hv.z * w2 + hv.w * w3;
        }
    }
#pragma unroll
    for (int r = 0; r < 4; ++r)
        xl2h[(size_t)(n0 + rg * 4 + r) * 128 + j] = __float2half_rn(acc[r]);
    float as = a_src2[j], ad = a_dst2[j];
    float ps[4], pd[4];
#pragma unroll
    for (int r = 0; r < 4; ++r) { ps[r] = acc[r] * as; pd[r] = acc[r] * ad; }
#pragma unroll
    for (int off = 32; off; off >>= 1) {
#pragma unroll
        for (int r = 0; r < 4; ++r) {
            ps[r] += __shfl_xor(ps[r], off);
            pd[r] += __shfl_xor(pd[r], off);
        }
    }
    int wave = t >> 6;
    if ((t & 63) == 0) {
#pragma unroll
        for (int r = 0; r < 4; ++r) { red[wave][r][0] = ps[r]; red[wave][r][1] = pd[r]; }
    }
    __syncthreads();
    if (t < 16) {
        int r = t & 3, g = t >> 2;   // node = n0 + g*4 + r, served by waves 2g, 2g+1
        es2[n0 + g * 4 + r] = red[2 * g][r][0] + red[2 * g + 1][r][0];
        ed2[n0 + g * 4 + r] = red[2 * g][r][1] + red[2 * g + 1][r][1];
    }
}

// MLP head: one block (128 threads) per graph
__global__ void mlp_kernel(const float* __restrict__ gsum, const float* __restrict__ gcnt,
                           const float* __restrict__ mw1, const float* __restrict__ mb1,
                           const float* __restrict__ mw2, const float* __restrict__ mb2,
                           float* __restrict__ out) {
    __shared__ float gm[128], tbuf[128];
    int g = blockIdx.x, j = threadIdx.x;
    float cnt = fmaxf(gcnt[g], 1.f);
    gm[j] = gsum[g * 128 + j] / cnt;
    __syncthreads();
    float s = mb1[j];
    for (int k = 0; k < 128; ++k) s += gm[k] * mw1[k * 128 + j];
    tbuf[j] = fmaxf(s, 0.f);
    __syncthreads();
    if (j < 4) {
        float o = mb2[j];
        for (int k = 0; k < 128; ++k) o += tbuf[k] * mw2[k * 4 + j];
        out[g * 4 + j] = o;
    }
}

extern "C" void kernel_launch(void* const* d_in, const int* in_sizes, int n_in,
                              void* d_out, int out_size, void* d_ws, size_t ws_size,
                              hipStream_t stream) {
    const float* x       = (const float*)d_in[0];
    const int*   ei      = (const int*)d_in[1];
    const int*   batch   = (const int*)d_in[2];
    const float* W1      = (const float*)d_in[3];
    const float* a_src1  = (const float*)d_in[4];
    const float* a_dst1  = (const float*)d_in[5];
    const float* b1      = (const float*)d_in[6];
    const float* W2      = (const float*)d_in[7];
    const float* a_src2  = (const float*)d_in[8];
    const float* a_dst2  = (const float*)d_in[9];
    const float* b2      = (const float*)d_in[10];
    const float* mw1     = (const float*)d_in[11];
    const float* mb1     = (const float*)d_in[12];
    const float* mw2     = (const float*)d_in[13];
    const float* mb2     = (const float*)d_in[14];
    float* out = (float*)d_out;

    const int N = in_sizes[0] / 6;      // 10000
    const int E = in_sizes[1] / 2;      // 160000
    const int ET = E + N;               // with self-loops
    const int G = 64;

    char* ws = (char*)d_ws;
    size_t off = 0;
    auto alloc = [&](size_t bytes) {
        void* p = ws + off;
        off += (bytes + 15) & ~(size_t)15;
        return p;
    };
    __half* xl1h   = (__half*)alloc((size_t)N * 512 * 2);
    float*  hbuf   = (float*)alloc((size_t)N * 512 * 4);
    __half* xl2h   = (__half*)alloc((size_t)N * 128 * 2);
    float*  es1    = (float*)alloc((size_t)N * 4 * 4);
    float*  ed1    = (float*)alloc((size_t)N * 4 * 4);
    float*  es2    = (float*)alloc((size_t)N * 4);
    float*  ed2    = (float*)alloc((size_t)N * 4);
    float*  dinv1  = (float*)alloc((size_t)N * 4 * 4);
    float*  dinv2  = (float*)alloc((size_t)N * 4);
    float*  alpha1 = (float*)alloc((size_t)ET * 4 * 4);
    float*  alpha2 = (float*)alloc((size_t)ET * 4);
    int*    offsets= (int*)alloc((size_t)(N + 1) * 4);
    int*    zbase  = (int*)alloc((size_t)N * 4 + (size_t)N * 4 + (size_t)G * 128 * 4 + (size_t)G * 4);
    int*    deg    = zbase;
    int*    cursor = zbase + N;
    float*  gsum   = (float*)(zbase + 2 * N);
    float*  gcnt   = gsum + G * 128;
    int*    csr_src= (int*)alloc((size_t)ET * 4);
    (void)ws_size; (void)n_in; (void)out_size;

    const int zn = 2 * N + G * 128 + G;

    zero_kernel<<<(zn + 255) / 256, 256, 0, stream>>>(zbase, zn);
    deg_kernel<<<(ET + 255) / 256, 256, 0, stream>>>(ei, E, N, deg);
    scan_kernel<<<1, 1024, 0, stream>>>(deg, offsets, N);
    fill_kernel<<<(ET + 255) / 256, 256, 0, stream>>>(ei, E, N, offsets, cursor, csr_src);

    xw1_attn<<<N, 256, 0, stream>>>(x, W1, a_src1, a_dst1, (__half2*)xl1h, es1, ed1, N);
    alpha_kernel<4><<<(N + 3) / 4, 256, 0, stream>>>(es1, ed1, offsets, csr_src, alpha1, dinv1, N);
    agg4_kernel<<<N / 4, 256, 0, stream>>>(xl1h, alpha1, dinv1, offsets, csr_src, b1, hbuf, N);
    xw2_attn<<<N / 16, 512, 0, stream>>>(hbuf, W2, a_src2, a_dst2, xl2h, es2, ed2, N);
    alpha_kernel<1><<<(N + 3) / 4, 256, 0, stream>>>(es2, ed2, offsets, csr_src, alpha2, dinv2, N);
    agg1_kernel<<<N / 4, 256, 0, stream>>>(xl2h, alpha2, dinv2, offsets, csr_src, b2,
                                           batch, gsum, gcnt, N);
    mlp_kernel<<<G, 128, 0, stream>>>(gsum, gcnt, mw1, mb1, mw2, mb2, out);
}

// Round 14
// 257.725 us; speedup vs baseline: 1.1403x; 1.1403x over previous
//
#include <hip/hip_runtime.h>
#include <hip/hip_fp16.h>

#define NEG_SLOPE 0.2f

typedef _Float16 f16x8 __attribute__((ext_vector_type(8)));
typedef float f32x4 __attribute__((ext_vector_type(4)));

// -------- edge helpers: edge_index is [2,E] int32 row-major; self-loops appended --------
__device__ __forceinline__ void edge_sd(const int* ei, int E, int e, int& s, int& d) {
    if (e < E) { s = ei[e]; d = ei[E + e]; }
    else       { int v = e - E; s = v; d = v; }
}

__global__ void zero_kernel(int* p, int n) {
    int i = blockIdx.x * blockDim.x + threadIdx.x;
    if (i < n) p[i] = 0;
}

__global__ void deg_kernel(const int* ei, int E, int N, int* deg) {
    int e = blockIdx.x * blockDim.x + threadIdx.x;
    if (e >= E + N) return;
    int s, d; edge_sd(ei, E, e, s, d);
    atomicAdd(&deg[d], 1);
}

// single-block exclusive scan of deg[0..n) -> offsets[0..n], offsets[n] = total
__global__ void scan_kernel(const int* deg, int* offsets, int n) {
    __shared__ int part[1024];
    int t = threadIdx.x;
    int chunk = (n + 1023) / 1024;
    int beg = t * chunk;
    int s = 0;
    for (int i = 0; i < chunk; ++i) {
        int idx = beg + i;
        if (idx < n) s += deg[idx];
    }
    part[t] = s;
    __syncthreads();
    for (int off = 1; off < 1024; off <<= 1) {
        int v = (t >= off) ? part[t - off] : 0;
        __syncthreads();
        part[t] += v;
        __syncthreads();
    }
    if (t == 1023) offsets[n] = part[1023];
    int run = (t == 0) ? 0 : part[t - 1];
    for (int i = 0; i < chunk; ++i) {
        int idx = beg + i;
        if (idx < n) { offsets[idx] = run; run += deg[idx]; }
    }
}

__global__ void fill_kernel(const int* ei, int E, int N, const int* offsets,
                            int* cursor, int* csr_src) {
    int e = blockIdx.x * blockDim.x + threadIdx.x;
    if (e >= E + N) return;
    int s, d; edge_sd(ei, E, e, s, d);
    int pos = offsets[d] + atomicAdd(&cursor[d], 1);
    csr_src[pos] = s;
}

// W2 [512][128] f32 -> W2t [128][512] fp16 (transposed). Output-indexed: contiguous
// 2B writes (512B/wave-instr); scattered 4B reads are L2-cached (W2 = 256KB).
__global__ void w2cvt_kernel(const float* __restrict__ W2, __half* __restrict__ W2t) {
    int i = blockIdx.x * 256 + threadIdx.x;   // i = c*512 + k, 65536 total
    int c = i >> 9, k = i & 511;
    W2t[i] = __float2half_rn(W2[k * 128 + c]);
}

// Fused: xl1 = x@W1 (per node, 512 outputs, stored fp16 for the gather path)
// + es1/ed1 attention scores (computed in f32). Block = 256 thr; wave = head.
__global__ void xw1_attn(const float* __restrict__ x, const float* __restrict__ W1,
                         const float* __restrict__ a_src, const float* __restrict__ a_dst,
                         __half2* __restrict__ xlh, float* __restrict__ es, float* __restrict__ ed,
                         int n) {
    int node = blockIdx.x;
    int t = threadIdx.x;
    __shared__ float xs[6];
    if (t < 6) xs[t] = x[node * 6 + t];
    __syncthreads();
    int j0 = 2 * t, j1 = 2 * t + 1;
    float v0 = 0.f, v1 = 0.f;
#pragma unroll
    for (int k = 0; k < 6; ++k) {
        v0 += xs[k] * W1[k * 512 + j0];
        v1 += xs[k] * W1[k * 512 + j1];
    }
    xlh[(size_t)node * 256 + t] = __floats2half2_rn(v0, v1);
    float ps = v0 * a_src[j0] + v1 * a_src[j1];
    float pd = v0 * a_dst[j0] + v1 * a_dst[j1];
#pragma unroll
    for (int off = 32; off; off >>= 1) {
        ps += __shfl_xor(ps, off);
        pd += __shfl_xor(pd, off);
    }
    int h = t >> 6, lane = t & 63;
    if (lane == 0) { es[node * 4 + h] = ps; ed[node * 4 + h] = pd; }
}

// Softmax weights, all H heads per wave. Wave per node (4 nodes / 256-thr block).
template <int H>
__global__ void alpha_kernel(const float* __restrict__ es, const float* __restrict__ ed,
                             const int* __restrict__ offsets, const int* __restrict__ csr_src,
                             float* __restrict__ alpha, float* __restrict__ dinv, int n) {
    int wave = threadIdx.x >> 6, lane = threadIdx.x & 63;
    int node = blockIdx.x * 4 + wave;
    if (node >= n) return;
    int beg = offsets[node], end = offsets[node + 1];
    float edv[H];
#pragma unroll
    for (int h = 0; h < H; ++h) edv[h] = ed[node * H + h];
    float sum[H];
#pragma unroll
    for (int h = 0; h < H; ++h) sum[h] = 0.f;
    for (int chunk = beg; chunk < end; chunk += 64) {
        int i = chunk + lane;
        bool valid = i < end;
        int s = valid ? csr_src[i] : 0;
        if (H == 4) {
            float4 e4 = valid ? *(const float4*)(es + (size_t)s * 4)
                              : make_float4(0.f, 0.f, 0.f, 0.f);
            float ev[4] = {e4.x, e4.y, e4.z, e4.w};
            float a[4];
#pragma unroll
            for (int h = 0; h < 4; ++h) {
                float w = ev[h] + edv[h];
                w = (w > 0.f) ? w : NEG_SLOPE * w;
                a[h] = valid ? __expf(w) : 0.f;
                sum[h] += a[h];
            }
            if (valid)
                *(float4*)(alpha + (size_t)i * 4) = make_float4(a[0], a[1], a[2], a[3]);
        } else {
            float w = (valid ? es[s] : 0.f) + edv[0];
            w = (w > 0.f) ? w : NEG_SLOPE * w;
            float a = valid ? __expf(w) : 0.f;
            sum[0] += a;
            if (valid) alpha[i] = a;
        }
    }
#pragma unroll
    for (int h = 0; h < H; ++h) {
        float s2 = sum[h];
#pragma unroll
        for (int off = 32; off; off >>= 1) s2 += __shfl_xor(s2, off);
        if (lane == 0) dinv[node * H + h] = 1.f / s2;
    }
}

// GAT1 aggregation, ALL 4 HEADS per wave (wave = node, 4 nodes / 256-thr block).
// Lane l covers channels 8l..8l+7 => each edge is ONE 1KB contiguous wave gather.
// Output hbuf stored fp16 NATURAL ORDER: 8ch/lane = one 16B store = 1KB contiguous
// wave store (fp16 removes the need for round-13's permuted layout).
__global__ void agg4_kernel(const __half* __restrict__ xlh, const float* __restrict__ alpha,
                            const float* __restrict__ dinv, const int* __restrict__ offsets,
                            const int* __restrict__ csr_src, const float* __restrict__ bias,
                            __half* __restrict__ outh, int n) {
    __shared__ int   s_src[4 * 64];
    __shared__ float s_al [4 * 64 * 4];
    int t = threadIdx.x, wave = t >> 6, lane = t & 63;
    int node = blockIdx.x * 4 + wave;
    int beg = offsets[node], end = offsets[node + 1];
    int woff = wave * 64;
    int hsel = lane >> 4;                 // head of channels 8l..8l+7
    float acc[8] = {0.f, 0.f, 0.f, 0.f, 0.f, 0.f, 0.f, 0.f};

    auto accum = [&](float4 r, float a) {
        const __half2* hp = (const __half2*)&r;
        float2 f0 = __half22float2(hp[0]), f1 = __half22float2(hp[1]);
        float2 f2 = __half22float2(hp[2]), f3 = __half22float2(hp[3]);
        acc[0] += a * f0.x; acc[1] += a * f0.y;
        acc[2] += a * f1.x; acc[3] += a * f1.y;
        acc[4] += a * f2.x; acc[5] += a * f2.y;
        acc[6] += a * f3.x; acc[7] += a * f3.y;
    };

    for (int chunk = beg; chunk < end; chunk += 64) {
        int i = chunk + lane;
        bool valid = i < end;
        s_src[woff + lane] = valid ? csr_src[i] : 0;
        float4 av = valid ? *(const float4*)(alpha + (size_t)i * 4)
                          : make_float4(0.f, 0.f, 0.f, 0.f);
        *(float4*)&s_al[(woff + lane) * 4] = av;
        int cnt = end - chunk; if (cnt > 64) cnt = 64;
        int base = 0;
        for (; base + 8 <= cnt; base += 8) {
            int s0 = s_src[woff+base+0], s1 = s_src[woff+base+1];
            int s2 = s_src[woff+base+2], s3 = s_src[woff+base+3];
            int s4 = s_src[woff+base+4], s5 = s_src[woff+base+5];
            int s6 = s_src[woff+base+6], s7 = s_src[woff+base+7];
            float a0 = s_al[(woff+base+0)*4 + hsel], a1 = s_al[(woff+base+1)*4 + hsel];
            float a2 = s_al[(woff+base+2)*4 + hsel], a3 = s_al[(woff+base+3)*4 + hsel];
            float a4 = s_al[(woff+base+4)*4 + hsel], a5 = s_al[(woff+base+5)*4 + hsel];
            float a6 = s_al[(woff+base+6)*4 + hsel], a7 = s_al[(woff+base+7)*4 + hsel];
            float4 r0 = *(const float4*)(xlh + (size_t)s0 * 512 + lane * 8);
            float4 r1 = *(const float4*)(xlh + (size_t)s1 * 512 + lane * 8);
            float4 r2 = *(const float4*)(xlh + (size_t)s2 * 512 + lane * 8);
            float4 r3 = *(const float4*)(xlh + (size_t)s3 * 512 + lane * 8);
            float4 r4 = *(const float4*)(xlh + (size_t)s4 * 512 + lane * 8);
            float4 r5 = *(const float4*)(xlh + (size_t)s5 * 512 + lane * 8);
            float4 r6 = *(const float4*)(xlh + (size_t)s6 * 512 + lane * 8);
            float4 r7 = *(const float4*)(xlh + (size_t)s7 * 512 + lane * 8);
            accum(r0, a0); accum(r1, a1); accum(r2, a2); accum(r3, a3);
            accum(r4, a4); accum(r5, a5); accum(r6, a6); accum(r7, a7);
        }
        for (; base < cnt; ++base) {
            int   sv = s_src[woff + base];
            float av1 = s_al[(woff + base) * 4 + hsel];
            float4 r = *(const float4*)(xlh + (size_t)sv * 512 + lane * 8);
            accum(r, av1);
        }
    }
    float inv = dinv[node * 4 + hsel];
    int c0 = lane * 8;
    float o[8];
#pragma unroll
    for (int k = 0; k < 8; ++k) o[k] = fmaxf(acc[k] * inv + bias[c0 + k], 0.f);
    float4 pack;
    ((__half2*)&pack)[0] = __floats2half2_rn(o[0], o[1]);
    ((__half2*)&pack)[1] = __floats2half2_rn(o[2], o[3]);
    ((__half2*)&pack)[2] = __floats2half2_rn(o[4], o[5]);
    ((__half2*)&pack)[3] = __floats2half2_rn(o[6], o[7]);
    *(float4*)(outh + (size_t)node * 512 + lane * 8) = pack;
}

// xl2 = h @ W2 via MFMA f16: [10000x512]@[512x128]. 625 blocks x 256 thr (4 waves).
// Wave w: cols 32w..32w+31 (2 tiles of 16), K-loop 16 steps of 32.
// Frags: lane l -> row/col = l&15, k = (l>>4)*8 + 0..7 (A/B symmetric; D layout per m89:
// col = lane&15, row = (lane>>4)*4 + reg). D -> LDS -> coalesced fp16 stores + fused
// es2/ed2 scores via 16-lane shfl reduce.
__global__ void __launch_bounds__(256)
xw2_mfma(const __half* __restrict__ h16, const __half* __restrict__ W2t,
         const float* __restrict__ a_src2, const float* __restrict__ a_dst2,
         __half* __restrict__ xl2h, float* __restrict__ es2, float* __restrict__ ed2, int n) {
    __shared__ float xs[16][132];     // [row][col], +4 pad
    int t = threadIdx.x, w = t >> 6, l = t & 63;
    int m0 = blockIdx.x * 16;
    int rc = l & 15, kg = l >> 4;     // rc = A-row / B-col / D-col; kg = k-group
    f32x4 acc0 = {0.f, 0.f, 0.f, 0.f}, acc1 = {0.f, 0.f, 0.f, 0.f};
    const __half* arow = h16 + (size_t)(m0 + rc) * 512 + kg * 8;
    const __half* b0p  = W2t + (size_t)(w * 32 + rc) * 512 + kg * 8;
    const __half* b1p  = W2t + (size_t)(w * 32 + 16 + rc) * 512 + kg * 8;
    for (int ks = 0; ks < 512; ks += 32) {
        f16x8 a  = *(const f16x8*)(arow + ks);
        f16x8 b0 = *(const f16x8*)(b0p + ks);
        f16x8 b1 = *(const f16x8*)(b1p + ks);
        acc0 = __builtin_amdgcn_mfma_f32_16x16x32_f16(a, b0, acc0, 0, 0, 0);
        acc1 = __builtin_amdgcn_mfma_f32_16x16x32_f16(a, b1, acc1, 0, 0, 0);
    }
#pragma unroll
    for (int i = 0; i < 4; ++i) {
        xs[kg * 4 + i][w * 32 + rc]      = acc0[i];
        xs[kg * 4 + i][w * 32 + 16 + rc] = acc1[i];
    }
    __syncthreads();
    int r = t >> 4, c0 = (t & 15) * 8;
    float v[8];
#pragma unroll
    for (int j = 0; j < 8; ++j) v[j] = xs[r][c0 + j];
    float4 pack;
    ((__half2*)&pack)[0] = __floats2half2_rn(v[0], v[1]);
    ((__half2*)&pack)[1] = __floats2half2_rn(v[2], v[3]);
    ((__half2*)&pack)[2] = __floats2half2_rn(v[4], v[5]);
    ((__half2*)&pack)[3] = __floats2half2_rn(v[6], v[7]);
    *(float4*)(xl2h + (size_t)(m0 + r) * 128 + c0) = pack;
    float ps = 0.f, pd = 0.f;
#pragma unroll
    for (int j = 0; j < 8; ++j) {
        ps += v[j] * a_src2[c0 + j];
        pd += v[j] * a_dst2[c0 + j];
    }
#pragma unroll
    for (int off = 8; off; off >>= 1) {
        ps += __shfl_xor(ps, off);
        pd += __shfl_xor(pd, off);
    }
    if ((l & 15) == 0) { es2[m0 + r] = ps; ed2[m0 + r] = pd; }
}

// GAT2 weighted gather (H=1), wide-load: 16 lanes x 16B per 256B row => 4 edges per
// instruction; LDS redistribute epilogue for contiguous stores; fused mean-pool.
__global__ void agg1_kernel(const __half* __restrict__ xlh, const float* __restrict__ alpha,
                            const float* __restrict__ dinv, const int* __restrict__ offsets,
                            const int* __restrict__ csr_src, const float* __restrict__ bias,
                            const int* __restrict__ batch,
                            float* __restrict__ gsum, float* __restrict__ gcnt, int n) {
    __shared__ int   s_src[4 * 64];
    __shared__ float s_al [4 * 64];
    __shared__ float s_red[4][64][8];
    int t = threadIdx.x, wave = t >> 6, lane = t & 63;
    int node = blockIdx.x * 4 + wave;
    int beg = offsets[node], end = offsets[node + 1];
    int woff = wave * 64;
    int lg = lane >> 4;
    int lc = lane & 15;
    float acc[8] = {0.f, 0.f, 0.f, 0.f, 0.f, 0.f, 0.f, 0.f};

    auto accum = [&](float4 r, float a) {
        const __half2* hp = (const __half2*)&r;
        float2 f0 = __half22float2(hp[0]), f1 = __half22float2(hp[1]);
        float2 f2 = __half22float2(hp[2]), f3 = __half22float2(hp[3]);
        acc[0] += a * f0.x; acc[1] += a * f0.y;
        acc[2] += a * f1.x; acc[3] += a * f1.y;
        acc[4] += a * f2.x; acc[5] += a * f2.y;
        acc[6] += a * f3.x; acc[7] += a * f3.y;
    };

    for (int chunk = beg; chunk < end; chunk += 64) {
        int i = chunk + lane;
        bool valid = i < end;
        s_src[woff + lane] = valid ? csr_src[i] : 0;
        s_al [woff + lane] = valid ? alpha[i] : 0.f;
        int cnt = end - chunk; if (cnt > 64) cnt = 64;
        int base = 0;
        for (; base + 16 <= cnt; base += 16) {
            int e0 = base + lg, e1 = base + 4 + lg, e2 = base + 8 + lg, e3 = base + 12 + lg;
            int   s0 = s_src[woff + e0], s1 = s_src[woff + e1];
            int   s2 = s_src[woff + e2], s3 = s_src[woff + e3];
            float a0 = s_al[woff + e0], a1 = s_al[woff + e1];
            float a2 = s_al[woff + e2], a3 = s_al[woff + e3];
            float4 r0 = *(const float4*)(xlh + (size_t)s0 * 128 + lc * 8);
            float4 r1 = *(const float4*)(xlh + (size_t)s1 * 128 + lc * 8);
            float4 r2 = *(const float4*)(xlh + (size_t)s2 * 128 + lc * 8);
            float4 r3 = *(const float4*)(xlh + (size_t)s3 * 128 + lc * 8);
            accum(r0, a0); accum(r1, a1); accum(r2, a2); accum(r3, a3);
        }
        for (; base < cnt; base += 4) {
            int eg = base + lg;
            bool v = eg < cnt;
            int   sv = v ? s_src[woff + eg] : 0;
            float av = v ? s_al[woff + eg] : 0.f;
            float4 r = *(const float4*)(xlh + (size_t)sv * 128 + lc * 8);
            accum(r, av);
        }
    }
    float4* dst = (float4*)&s_red[wave][lane][0];
    dst[0] = make_float4(acc[0], acc[1], acc[2], acc[3]);
    dst[1] = make_float4(acc[4], acc[5], acc[6], acc[7]);
    int lcs = lane >> 2;
    int pe  = lane & 3;
    float vx = 0.f, vy = 0.f;
#pragma unroll
    for (int g = 0; g < 4; ++g) {
        float2 p = ((float2*)&s_red[wave][g * 16 + lcs][0])[pe];
        vx += p.x; vy += p.y;
    }
    float inv = dinv[node];
    int j0 = 2 * lane;
    float o0 = fmaxf(vx * inv + bias[j0], 0.f);
    float o1 = fmaxf(vy * inv + bias[j0 + 1], 0.f);
    int b = batch[node];
    atomicAdd(&gsum[b * 128 + j0], o0);
    atomicAdd(&gsum[b * 128 + j0 + 1], o1);
    if (lane == 0) atomicAdd(&gcnt[b], 1.f);
}

// MLP head: one block (128 threads) per graph
__global__ void mlp_kernel(const float* __restrict__ gsum, const float* __restrict__ gcnt,
                           const float* __restrict__ mw1, const float* __restrict__ mb1,
                           const float* __restrict__ mw2, const float* __restrict__ mb2,
                           float* __restrict__ out) {
    __shared__ float gm[128], tbuf[128];
    int g = blockIdx.x, j = threadIdx.x;
    float cnt = fmaxf(gcnt[g], 1.f);
    gm[j] = gsum[g * 128 + j] / cnt;
    __syncthreads();
    float s = mb1[j];
    for (int k = 0; k < 128; ++k) s += gm[k] * mw1[k * 128 + j];
    tbuf[j] = fmaxf(s, 0.f);
    __syncthreads();
    if (j < 4) {
        float o = mb2[j];
        for (int k = 0; k < 128; ++k) o += tbuf[k] * mw2[k * 4 + j];
        out[g * 4 + j] = o;
    }
}

extern "C" void kernel_launch(void* const* d_in, const int* in_sizes, int n_in,
                              void* d_out, int out_size, void* d_ws, size_t ws_size,
                              hipStream_t stream) {
    const float* x       = (const float*)d_in[0];
    const int*   ei      = (const int*)d_in[1];
    const int*   batch   = (const int*)d_in[2];
    const float* W1      = (const float*)d_in[3];
    const float* a_src1  = (const float*)d_in[4];
    const float* a_dst1  = (const float*)d_in[5];
    const float* b1      = (const float*)d_in[6];
    const float* W2      = (const float*)d_in[7];
    const float* a_src2  = (const float*)d_in[8];
    const float* a_dst2  = (const float*)d_in[9];
    const float* b2      = (const float*)d_in[10];
    const float* mw1     = (const float*)d_in[11];
    const float* mb1     = (const float*)d_in[12];
    const float* mw2     = (const float*)d_in[13];
    const float* mb2     = (const float*)d_in[14];
    float* out = (float*)d_out;

    const int N = in_sizes[0] / 6;      // 10000
    const int E = in_sizes[1] / 2;      // 160000
    const int ET = E + N;               // with self-loops
    const int G = 64;

    char* ws = (char*)d_ws;
    size_t off = 0;
    auto alloc = [&](size_t bytes) {
        void* p = ws + off;
        off += (bytes + 15) & ~(size_t)15;
        return p;
    };
    __half* xl1h   = (__half*)alloc((size_t)N * 512 * 2);
    __half* hbufh  = (__half*)alloc((size_t)N * 512 * 2);
    __half* xl2h   = (__half*)alloc((size_t)N * 128 * 2);
    __half* W2t    = (__half*)alloc((size_t)512 * 128 * 2);
    float*  es1    = (float*)alloc((size_t)N * 4 * 4);
    float*  ed1    = (float*)alloc((size_t)N * 4 * 4);
    float*  es2    = (float*)alloc((size_t)N * 4);
    float*  ed2    = (float*)alloc((size_t)N * 4);
    float*  dinv1  = (float*)alloc((size_t)N * 4 * 4);
    float*  dinv2  = (float*)alloc((size_t)N * 4);
    float*  alpha1 = (float*)alloc((size_t)ET * 4 * 4);
    float*  alpha2 = (float*)alloc((size_t)ET * 4);
    int*    offsets= (int*)alloc((size_t)(N + 1) * 4);
    int*    zbase  = (int*)alloc((size_t)N * 4 + (size_t)N * 4 + (size_t)G * 128 * 4 + (size_t)G * 4);
    int*    deg    = zbase;
    int*    cursor = zbase + N;
    float*  gsum   = (float*)(zbase + 2 * N);
    float*  gcnt   = gsum + G * 128;
    int*    csr_src= (int*)alloc((size_t)ET * 4);
    (void)ws_size; (void)n_in; (void)out_size;

    const int zn = 2 * N + G * 128 + G;

    zero_kernel<<<(zn + 255) / 256, 256, 0, stream>>>(zbase, zn);
    deg_kernel<<<(ET + 255) / 256, 256, 0, stream>>>(ei, E, N, deg);
    w2cvt_kernel<<<(512 * 128) / 256, 256, 0, stream>>>(W2, W2t);
    scan_kernel<<<1, 1024, 0, stream>>>(deg, offsets, N);
    fill_kernel<<<(ET + 255) / 256, 256, 0, stream>>>(ei, E, N, offsets, cursor, csr_src);

    xw1_attn<<<N, 256, 0, stream>>>(x, W1, a_src1, a_dst1, (__half2*)xl1h, es1, ed1, N);
    alpha_kernel<4><<<(N + 3) / 4, 256, 0, stream>>>(es1, ed1, offsets, csr_src, alpha1, dinv1, N);
    agg4_kernel<<<N / 4, 256, 0, stream>>>(xl1h, alpha1, dinv1, offsets, csr_src, b1, hbufh, N);
    xw2_mfma<<<N / 16, 256, 0, stream>>>(hbufh, W2t, a_src2, a_dst2, xl2h, es2, ed2, N);
    alpha_kernel<1><<<(N + 3) / 4, 256, 0, stream>>>(es2, ed2, offsets, csr_src, alpha2, dinv2, N);
    agg1_kernel<<<N / 4, 256, 0, stream>>>(xl2h, alpha2, dinv2, offsets, csr_src, b2,
                                           batch, gsum, gcnt, N);
    mlp_kernel<<<G, 128, 0, stream>>>(gsum, gcnt, mw1, mb1, mw2, mb2, out);
}

// Round 15
// 209.597 us; speedup vs baseline: 1.4021x; 1.2296x over previous
//
#include <hip/hip_runtime.h>
#include <hip/hip_fp16.h>

#define NEG_SLOPE 0.2f

typedef _Float16 f16x8 __attribute__((ext_vector_type(8)));
typedef float f32x4 __attribute__((ext_vector_type(4)));

// -------- edge helpers: edge_index is [2,E] int32 row-major; self-loops appended --------
__device__ __forceinline__ void edge_sd(const int* ei, int E, int e, int& s, int& d) {
    if (e < E) { s = ei[e]; d = ei[E + e]; }
    else       { int v = e - E; s = v; d = v; }
}

__global__ void zero_kernel(int* p, int n) {
    int i = blockIdx.x * blockDim.x + threadIdx.x;
    if (i < n) p[i] = 0;
}

__global__ void deg_kernel(const int* ei, int E, int N, int* deg) {
    int e = blockIdx.x * blockDim.x + threadIdx.x;
    if (e >= E + N) return;
    int s, d; edge_sd(ei, E, e, s, d);
    atomicAdd(&deg[d], 1);
}

// single-block exclusive scan of deg[0..n) -> offsets[0..n], offsets[n] = total
__global__ void scan_kernel(const int* deg, int* offsets, int n) {
    __shared__ int part[1024];
    int t = threadIdx.x;
    int chunk = (n + 1023) / 1024;
    int beg = t * chunk;
    int s = 0;
    for (int i = 0; i < chunk; ++i) {
        int idx = beg + i;
        if (idx < n) s += deg[idx];
    }
    part[t] = s;
    __syncthreads();
    for (int off = 1; off < 1024; off <<= 1) {
        int v = (t >= off) ? part[t - off] : 0;
        __syncthreads();
        part[t] += v;
        __syncthreads();
    }
    if (t == 1023) offsets[n] = part[1023];
    int run = (t == 0) ? 0 : part[t - 1];
    for (int i = 0; i < chunk; ++i) {
        int idx = beg + i;
        if (idx < n) { offsets[idx] = run; run += deg[idx]; }
    }
}

__global__ void fill_kernel(const int* ei, int E, int N, const int* offsets,
                            int* cursor, int* csr_src) {
    int e = blockIdx.x * blockDim.x + threadIdx.x;
    if (e >= E + N) return;
    int s, d; edge_sd(ei, E, e, s, d);
    int pos = offsets[d] + atomicAdd(&cursor[d], 1);
    csr_src[pos] = s;
}

// W2 [512][128] f32 -> W2t [128][512] fp16 (transposed). Output-indexed: contiguous
// 2B writes; scattered 4B reads are L2-cached (W2 = 256KB).
__global__ void w2cvt_kernel(const float* __restrict__ W2, __half* __restrict__ W2t) {
    int i = blockIdx.x * 256 + threadIdx.x;   // i = c*512 + k, 65536 total
    int c = i >> 9, k = i & 511;
    W2t[i] = __float2half_rn(W2[k * 128 + c]);
}

// Fused: xl1 = x@W1 (per node, 512 outputs, stored fp16 for the gather path)
// + es1/ed1 attention scores (computed in f32). Block = 256 thr; wave = head.
__global__ void xw1_attn(const float* __restrict__ x, const float* __restrict__ W1,
                         const float* __restrict__ a_src, const float* __restrict__ a_dst,
                         __half2* __restrict__ xlh, float* __restrict__ es, float* __restrict__ ed,
                         int n) {
    int node = blockIdx.x;
    int t = threadIdx.x;
    __shared__ float xs[6];
    if (t < 6) xs[t] = x[node * 6 + t];
    __syncthreads();
    int j0 = 2 * t, j1 = 2 * t + 1;
    float v0 = 0.f, v1 = 0.f;
#pragma unroll
    for (int k = 0; k < 6; ++k) {
        v0 += xs[k] * W1[k * 512 + j0];
        v1 += xs[k] * W1[k * 512 + j1];
    }
    xlh[(size_t)node * 256 + t] = __floats2half2_rn(v0, v1);
    float ps = v0 * a_src[j0] + v1 * a_src[j1];
    float pd = v0 * a_dst[j0] + v1 * a_dst[j1];
#pragma unroll
    for (int off = 32; off; off >>= 1) {
        ps += __shfl_xor(ps, off);
        pd += __shfl_xor(pd, off);
    }
    int h = t >> 6, lane = t & 63;
    if (lane == 0) { es[node * 4 + h] = ps; ed[node * 4 + h] = pd; }
}

// Softmax weights, all H heads per wave. Wave per node (4 nodes / 256-thr block).
template <int H>
__global__ void alpha_kernel(const float* __restrict__ es, const float* __restrict__ ed,
                             const int* __restrict__ offsets, const int* __restrict__ csr_src,
                             float* __restrict__ alpha, float* __restrict__ dinv, int n) {
    int wave = threadIdx.x >> 6, lane = threadIdx.x & 63;
    int node = blockIdx.x * 4 + wave;
    if (node >= n) return;
    int beg = offsets[node], end = offsets[node + 1];
    float edv[H];
#pragma unroll
    for (int h = 0; h < H; ++h) edv[h] = ed[node * H + h];
    float sum[H];
#pragma unroll
    for (int h = 0; h < H; ++h) sum[h] = 0.f;
    for (int chunk = beg; chunk < end; chunk += 64) {
        int i = chunk + lane;
        bool valid = i < end;
        int s = valid ? csr_src[i] : 0;
        if (H == 4) {
            float4 e4 = valid ? *(const float4*)(es + (size_t)s * 4)
                              : make_float4(0.f, 0.f, 0.f, 0.f);
            float ev[4] = {e4.x, e4.y, e4.z, e4.w};
            float a[4];
#pragma unroll
            for (int h = 0; h < 4; ++h) {
                float w = ev[h] + edv[h];
                w = (w > 0.f) ? w : NEG_SLOPE * w;
                a[h] = valid ? __expf(w) : 0.f;
                sum[h] += a[h];
            }
            if (valid)
                *(float4*)(alpha + (size_t)i * 4) = make_float4(a[0], a[1], a[2], a[3]);
        } else {
            float w = (valid ? es[s] : 0.f) + edv[0];
            w = (w > 0.f) ? w : NEG_SLOPE * w;
            float a = valid ? __expf(w) : 0.f;
            sum[0] += a;
            if (valid) alpha[i] = a;
        }
    }
#pragma unroll
    for (int h = 0; h < H; ++h) {
        float s2 = sum[h];
#pragma unroll
        for (int off = 32; off; off >>= 1) s2 += __shfl_xor(s2, off);
        if (lane == 0) dinv[node * H + h] = 1.f / s2;
    }
}

// GAT1 aggregation, ALL 4 HEADS per wave (wave = node, 4 nodes / 256-thr block).
// Lane l covers channels 8l..8l+7 => each edge is ONE 1KB contiguous wave gather.
// Output hbuf stored fp16 natural order (one 16B store/lane = 1KB contiguous).
__global__ void agg4_kernel(const __half* __restrict__ xlh, const float* __restrict__ alpha,
                            const float* __restrict__ dinv, const int* __restrict__ offsets,
                            const int* __restrict__ csr_src, const float* __restrict__ bias,
                            __half* __restrict__ outh, int n) {
    __shared__ int   s_src[4 * 64];
    __shared__ float s_al [4 * 64 * 4];
    int t = threadIdx.x, wave = t >> 6, lane = t & 63;
    int node = blockIdx.x * 4 + wave;
    int beg = offsets[node], end = offsets[node + 1];
    int woff = wave * 64;
    int hsel = lane >> 4;                 // head of channels 8l..8l+7
    float acc[8] = {0.f, 0.f, 0.f, 0.f, 0.f, 0.f, 0.f, 0.f};

    auto accum = [&](float4 r, float a) {
        const __half2* hp = (const __half2*)&r;
        float2 f0 = __half22float2(hp[0]), f1 = __half22float2(hp[1]);
        float2 f2 = __half22float2(hp[2]), f3 = __half22float2(hp[3]);
        acc[0] += a * f0.x; acc[1] += a * f0.y;
        acc[2] += a * f1.x; acc[3] += a * f1.y;
        acc[4] += a * f2.x; acc[5] += a * f2.y;
        acc[6] += a * f3.x; acc[7] += a * f3.y;
    };

    for (int chunk = beg; chunk < end; chunk += 64) {
        int i = chunk + lane;
        bool valid = i < end;
        s_src[woff + lane] = valid ? csr_src[i] : 0;
        float4 av = valid ? *(const float4*)(alpha + (size_t)i * 4)
                          : make_float4(0.f, 0.f, 0.f, 0.f);
        *(float4*)&s_al[(woff + lane) * 4] = av;
        int cnt = end - chunk; if (cnt > 64) cnt = 64;
        int base = 0;
        for (; base + 8 <= cnt; base += 8) {
            int s0 = s_src[woff+base+0], s1 = s_src[woff+base+1];
            int s2 = s_src[woff+base+2], s3 = s_src[woff+base+3];
            int s4 = s_src[woff+base+4], s5 = s_src[woff+base+5];
            int s6 = s_src[woff+base+6], s7 = s_src[woff+base+7];
            float a0 = s_al[(woff+base+0)*4 + hsel], a1 = s_al[(woff+base+1)*4 + hsel];
            float a2 = s_al[(woff+base+2)*4 + hsel], a3 = s_al[(woff+base+3)*4 + hsel];
            float a4 = s_al[(woff+base+4)*4 + hsel], a5 = s_al[(woff+base+5)*4 + hsel];
            float a6 = s_al[(woff+base+6)*4 + hsel], a7 = s_al[(woff+base+7)*4 + hsel];
            float4 r0 = *(const float4*)(xlh + (size_t)s0 * 512 + lane * 8);
            float4 r1 = *(const float4*)(xlh + (size_t)s1 * 512 + lane * 8);
            float4 r2 = *(const float4*)(xlh + (size_t)s2 * 512 + lane * 8);
            float4 r3 = *(const float4*)(xlh + (size_t)s3 * 512 + lane * 8);
            float4 r4 = *(const float4*)(xlh + (size_t)s4 * 512 + lane * 8);
            float4 r5 = *(const float4*)(xlh + (size_t)s5 * 512 + lane * 8);
            float4 r6 = *(const float4*)(xlh + (size_t)s6 * 512 + lane * 8);
            float4 r7 = *(const float4*)(xlh + (size_t)s7 * 512 + lane * 8);
            accum(r0, a0); accum(r1, a1); accum(r2, a2); accum(r3, a3);
            accum(r4, a4); accum(r5, a5); accum(r6, a6); accum(r7, a7);
        }
        for (; base < cnt; ++base) {
            int   sv = s_src[woff + base];
            float av1 = s_al[(woff + base) * 4 + hsel];
            float4 r = *(const float4*)(xlh + (size_t)sv * 512 + lane * 8);
            accum(r, av1);
        }
    }
    float inv = dinv[node * 4 + hsel];
    int c0 = lane * 8;
    float o[8];
#pragma unroll
    for (int k = 0; k < 8; ++k) o[k] = fmaxf(acc[k] * inv + bias[c0 + k], 0.f);
    float4 pack;
    ((__half2*)&pack)[0] = __floats2half2_rn(o[0], o[1]);
    ((__half2*)&pack)[1] = __floats2half2_rn(o[2], o[3]);
    ((__half2*)&pack)[2] = __floats2half2_rn(o[4], o[5]);
    ((__half2*)&pack)[3] = __floats2half2_rn(o[6], o[7]);
    *(float4*)(outh + (size_t)node * 512 + lane * 8) = pack;
}

// xl2 = h @ W2 via MFMA f16: [10000x512]@[512x128]. 625 blocks x 256 thr (4 waves).
__global__ void __launch_bounds__(256)
xw2_mfma(const __half* __restrict__ h16, const __half* __restrict__ W2t,
         const float* __restrict__ a_src2, const float* __restrict__ a_dst2,
         __half* __restrict__ xl2h, float* __restrict__ es2, float* __restrict__ ed2, int n) {
    __shared__ float xs[16][132];     // [row][col], +4 pad
    int t = threadIdx.x, w = t >> 6, l = t & 63;
    int m0 = blockIdx.x * 16;
    int rc = l & 15, kg = l >> 4;
    f32x4 acc0 = {0.f, 0.f, 0.f, 0.f}, acc1 = {0.f, 0.f, 0.f, 0.f};
    const __half* arow = h16 + (size_t)(m0 + rc) * 512 + kg * 8;
    const __half* b0p  = W2t + (size_t)(w * 32 + rc) * 512 + kg * 8;
    const __half* b1p  = W2t + (size_t)(w * 32 + 16 + rc) * 512 + kg * 8;
    for (int ks = 0; ks < 512; ks += 32) {
        f16x8 a  = *(const f16x8*)(arow + ks);
        f16x8 b0 = *(const f16x8*)(b0p + ks);
        f16x8 b1 = *(const f16x8*)(b1p + ks);
        acc0 = __builtin_amdgcn_mfma_f32_16x16x32_f16(a, b0, acc0, 0, 0, 0);
        acc1 = __builtin_amdgcn_mfma_f32_16x16x32_f16(a, b1, acc1, 0, 0, 0);
    }
#pragma unroll
    for (int i = 0; i < 4; ++i) {
        xs[kg * 4 + i][w * 32 + rc]      = acc0[i];
        xs[kg * 4 + i][w * 32 + 16 + rc] = acc1[i];
    }
    __syncthreads();
    int r = t >> 4, c0 = (t & 15) * 8;
    float v[8];
#pragma unroll
    for (int j = 0; j < 8; ++j) v[j] = xs[r][c0 + j];
    float4 pack;
    ((__half2*)&pack)[0] = __floats2half2_rn(v[0], v[1]);
    ((__half2*)&pack)[1] = __floats2half2_rn(v[2], v[3]);
    ((__half2*)&pack)[2] = __floats2half2_rn(v[4], v[5]);
    ((__half2*)&pack)[3] = __floats2half2_rn(v[6], v[7]);
    *(float4*)(xl2h + (size_t)(m0 + r) * 128 + c0) = pack;
    float ps = 0.f, pd = 0.f;
#pragma unroll
    for (int j = 0; j < 8; ++j) {
        ps += v[j] * a_src2[c0 + j];
        pd += v[j] * a_dst2[c0 + j];
    }
#pragma unroll
    for (int off = 8; off; off >>= 1) {
        ps += __shfl_xor(ps, off);
        pd += __shfl_xor(pd, off);
    }
    if ((l & 15) == 0) { es2[m0 + r] = ps; ed2[m0 + r] = pd; }
}

// GAT2 weighted gather (H=1), wide-load; LDS redistribute epilogue; contiguous
// float2 stores to h2 (NO atomics -- pool moved to pool_mlp_kernel).
__global__ void agg1_kernel(const __half* __restrict__ xlh, const float* __restrict__ alpha,
                            const float* __restrict__ dinv, const int* __restrict__ offsets,
                            const int* __restrict__ csr_src, const float* __restrict__ bias,
                            float* __restrict__ h2, int n) {
    __shared__ int   s_src[4 * 64];
    __shared__ float s_al [4 * 64];
    __shared__ float s_red[4][64][8];
    int t = threadIdx.x, wave = t >> 6, lane = t & 63;
    int node = blockIdx.x * 4 + wave;
    int beg = offsets[node], end = offsets[node + 1];
    int woff = wave * 64;
    int lg = lane >> 4;
    int lc = lane & 15;
    float acc[8] = {0.f, 0.f, 0.f, 0.f, 0.f, 0.f, 0.f, 0.f};

    auto accum = [&](float4 r, float a) {
        const __half2* hp = (const __half2*)&r;
        float2 f0 = __half22float2(hp[0]), f1 = __half22float2(hp[1]);
        float2 f2 = __half22float2(hp[2]), f3 = __half22float2(hp[3]);
        acc[0] += a * f0.x; acc[1] += a * f0.y;
        acc[2] += a * f1.x; acc[3] += a * f1.y;
        acc[4] += a * f2.x; acc[5] += a * f2.y;
        acc[6] += a * f3.x; acc[7] += a * f3.y;
    };

    for (int chunk = beg; chunk < end; chunk += 64) {
        int i = chunk + lane;
        bool valid = i < end;
        s_src[woff + lane] = valid ? csr_src[i] : 0;
        s_al [woff + lane] = valid ? alpha[i] : 0.f;
        int cnt = end - chunk; if (cnt > 64) cnt = 64;
        int base = 0;
        for (; base + 16 <= cnt; base += 16) {
            int e0 = base + lg, e1 = base + 4 + lg, e2 = base + 8 + lg, e3 = base + 12 + lg;
            int   s0 = s_src[woff + e0], s1 = s_src[woff + e1];
            int   s2 = s_src[woff + e2], s3 = s_src[woff + e3];
            float a0 = s_al[woff + e0], a1 = s_al[woff + e1];
            float a2 = s_al[woff + e2], a3 = s_al[woff + e3];
            float4 r0 = *(const float4*)(xlh + (size_t)s0 * 128 + lc * 8);
            float4 r1 = *(const float4*)(xlh + (size_t)s1 * 128 + lc * 8);
            float4 r2 = *(const float4*)(xlh + (size_t)s2 * 128 + lc * 8);
            float4 r3 = *(const float4*)(xlh + (size_t)s3 * 128 + lc * 8);
            accum(r0, a0); accum(r1, a1); accum(r2, a2); accum(r3, a3);
        }
        for (; base < cnt; base += 4) {
            int eg = base + lg;
            bool v = eg < cnt;
            int   sv = v ? s_src[woff + eg] : 0;
            float av = v ? s_al[woff + eg] : 0.f;
            float4 r = *(const float4*)(xlh + (size_t)sv * 128 + lc * 8);
            accum(r, av);
        }
    }
    float4* dst = (float4*)&s_red[wave][lane][0];
    dst[0] = make_float4(acc[0], acc[1], acc[2], acc[3]);
    dst[1] = make_float4(acc[4], acc[5], acc[6], acc[7]);
    int lcs = lane >> 2;
    int pe  = lane & 3;
    float vx = 0.f, vy = 0.f;
#pragma unroll
    for (int g = 0; g < 4; ++g) {
        float2 p = ((float2*)&s_red[wave][g * 16 + lcs][0])[pe];
        vx += p.x; vy += p.y;
    }
    float inv = dinv[node];
    int j0 = 2 * lane;
    float o0 = fmaxf(vx * inv + bias[j0], 0.f);
    float o1 = fmaxf(vy * inv + bias[j0 + 1], 0.f);
    float2* op = (float2*)(h2 + (size_t)node * 128);
    op[lane] = make_float2(o0, o1);
}

__device__ __forceinline__ int lower_bound_i(const int* a, int n, int key) {
    int lo = 0, hi = n;
    while (lo < hi) {
        int mid = (lo + hi) >> 1;
        if (a[mid] < key) lo = mid + 1; else hi = mid;
    }
    return lo;
}

// Fused mean-pool + MLP head. One block (512 thr) per graph; batch is SORTED so
// graph g owns contiguous node range [lb(g), lb(g+1)) found by binary search.
// NO atomics: 4-way node-split row sum + LDS reduce, then the 2-layer MLP.
__global__ void __launch_bounds__(512)
pool_mlp_kernel(const float* __restrict__ h2, const int* __restrict__ batch,
                const float* __restrict__ mw1, const float* __restrict__ mb1,
                const float* __restrict__ mw2, const float* __restrict__ mb2,
                float* __restrict__ out, int n) {
    __shared__ float part[4][128];
    __shared__ float gm[128], tbuf[128];
    int g = blockIdx.x, t = threadIdx.x;
    int j = t & 127, rg = t >> 7;
    int a = lower_bound_i(batch, n, g);
    int b = lower_bound_i(batch, n, g + 1);
    float s = 0.f;
    for (int i = a + rg; i < b; i += 4) s += h2[(size_t)i * 128 + j];
    part[rg][j] = s;
    __syncthreads();
    if (t < 128) {
        float cnt = fmaxf((float)(b - a), 1.f);
        gm[j] = (part[0][j] + part[1][j] + part[2][j] + part[3][j]) / cnt;
    }
    __syncthreads();
    if (t < 128) {
        float v = mb1[j];
        for (int k = 0; k < 128; ++k) v += gm[k] * mw1[k * 128 + j];
        tbuf[j] = fmaxf(v, 0.f);
    }
    __syncthreads();
    if (t < 4) {
        float o = mb2[t];
        for (int k = 0; k < 128; ++k) o += tbuf[k] * mw2[k * 4 + t];
        out[g * 4 + t] = o;
    }
}

extern "C" void kernel_launch(void* const* d_in, const int* in_sizes, int n_in,
                              void* d_out, int out_size, void* d_ws, size_t ws_size,
                              hipStream_t stream) {
    const float* x       = (const float*)d_in[0];
    const int*   ei      = (const int*)d_in[1];
    const int*   batch   = (const int*)d_in[2];
    const float* W1      = (const float*)d_in[3];
    const float* a_src1  = (const float*)d_in[4];
    const float* a_dst1  = (const float*)d_in[5];
    const float* b1      = (const float*)d_in[6];
    const float* W2      = (const float*)d_in[7];
    const float* a_src2  = (const float*)d_in[8];
    const float* a_dst2  = (const float*)d_in[9];
    const float* b2      = (const float*)d_in[10];
    const float* mw1     = (const float*)d_in[11];
    const float* mb1     = (const float*)d_in[12];
    const float* mw2     = (const float*)d_in[13];
    const float* mb2     = (const float*)d_in[14];
    float* out = (float*)d_out;

    const int N = in_sizes[0] / 6;      // 10000
    const int E = in_sizes[1] / 2;      // 160000
    const int ET = E + N;               // with self-loops
    const int G = 64;

    char* ws = (char*)d_ws;
    size_t off = 0;
    auto alloc = [&](size_t bytes) {
        void* p = ws + off;
        off += (bytes + 15) & ~(size_t)15;
        return p;
    };
    __half* xl1h   = (__half*)alloc((size_t)N * 512 * 2);
    __half* hbufh  = (__half*)alloc((size_t)N * 512 * 2);
    __half* xl2h   = (__half*)alloc((size_t)N * 128 * 2);
    float*  h2     = (float*)alloc((size_t)N * 128 * 4);
    __half* W2t    = (__half*)alloc((size_t)512 * 128 * 2);
    float*  es1    = (float*)alloc((size_t)N * 4 * 4);
    float*  ed1    = (float*)alloc((size_t)N * 4 * 4);
    float*  es2    = (float*)alloc((size_t)N * 4);
    float*  ed2    = (float*)alloc((size_t)N * 4);
    float*  dinv1  = (float*)alloc((size_t)N * 4 * 4);
    float*  dinv2  = (float*)alloc((size_t)N * 4);
    float*  alpha1 = (float*)alloc((size_t)ET * 4 * 4);
    float*  alpha2 = (float*)alloc((size_t)ET * 4);
    int*    offsets= (int*)alloc((size_t)(N + 1) * 4);
    int*    zbase  = (int*)alloc((size_t)N * 4 + (size_t)N * 4);
    int*    deg    = zbase;
    int*    cursor = zbase + N;
    int*    csr_src= (int*)alloc((size_t)ET * 4);
    (void)ws_size; (void)n_in; (void)out_size;

    const int zn = 2 * N;

    zero_kernel<<<(zn + 255) / 256, 256, 0, stream>>>(zbase, zn);
    deg_kernel<<<(ET + 255) / 256, 256, 0, stream>>>(ei, E, N, deg);
    w2cvt_kernel<<<(512 * 128) / 256, 256, 0, stream>>>(W2, W2t);
    scan_kernel<<<1, 1024, 0, stream>>>(deg, offsets, N);
    fill_kernel<<<(ET + 255) / 256, 256, 0, stream>>>(ei, E, N, offsets, cursor, csr_src);

    xw1_attn<<<N, 256, 0, stream>>>(x, W1, a_src1, a_dst1, (__half2*)xl1h, es1, ed1, N);
    alpha_kernel<4><<<(N + 3) / 4, 256, 0, stream>>>(es1, ed1, offsets, csr_src, alpha1, dinv1, N);
    agg4_kernel<<<N / 4, 256, 0, stream>>>(xl1h, alpha1, dinv1, offsets, csr_src, b1, hbufh, N);
    xw2_mfma<<<N / 16, 256, 0, stream>>>(hbufh, W2t, a_src2, a_dst2, xl2h, es2, ed2, N);
    alpha_kernel<1><<<(N + 3) / 4, 256, 0, stream>>>(es2, ed2, offsets, csr_src, alpha2, dinv2, N);
    agg1_kernel<<<N / 4, 256, 0, stream>>>(xl2h, alpha2, dinv2, offsets, csr_src, b2, h2, N);
    pool_mlp_kernel<<<G, 512, 0, stream>>>(h2, batch, mw1, mb1, mw2, mb2, out, N);
}

// Round 16
// 198.736 us; speedup vs baseline: 1.4788x; 1.0547x over previous
//
#include <hip/hip_runtime.h>
#include <hip/hip_fp16.h>

#define NEG_SLOPE 0.2f

typedef _Float16 f16x8 __attribute__((ext_vector_type(8)));
typedef float f32x4 __attribute__((ext_vector_type(4)));

// -------- edge helpers: edge_index is [2,E] int32 row-major; self-loops appended --------
__device__ __forceinline__ void edge_sd(const int* ei, int E, int e, int& s, int& d) {
    if (e < E) { s = ei[e]; d = ei[E + e]; }
    else       { int v = e - E; s = v; d = v; }
}

// Merged setup: i<65536 -> W2 transpose+fp16 cvt; else zero deg/cursor.
__global__ void setup_kernel(const float* __restrict__ W2, __half* __restrict__ W2t,
                             int* __restrict__ zbase, int zn) {
    int i = blockIdx.x * 256 + threadIdx.x;
    if (i < 65536) {
        int c = i >> 9, k = i & 511;
        W2t[i] = __float2half_rn(W2[k * 128 + c]);
    } else if (i - 65536 < zn) {
        zbase[i - 65536] = 0;
    }
}

// single-block exclusive scan of deg[0..n) -> offsets[0..n], offsets[n] = total
__global__ void scan_kernel(const int* deg, int* offsets, int n) {
    __shared__ int part[1024];
    int t = threadIdx.x;
    int chunk = (n + 1023) / 1024;
    int beg = t * chunk;
    int s = 0;
    for (int i = 0; i < chunk; ++i) {
        int idx = beg + i;
        if (idx < n) s += deg[idx];
    }
    part[t] = s;
    __syncthreads();
    for (int off = 1; off < 1024; off <<= 1) {
        int v = (t >= off) ? part[t - off] : 0;
        __syncthreads();
        part[t] += v;
        __syncthreads();
    }
    if (t == 1023) offsets[n] = part[1023];
    int run = (t == 0) ? 0 : part[t - 1];
    for (int i = 0; i < chunk; ++i) {
        int idx = beg + i;
        if (idx < n) { offsets[idx] = run; run += deg[idx]; }
    }
}

__global__ void fill_kernel(const int* ei, int E, int N, const int* offsets,
                            int* cursor, int* csr_src) {
    int e = blockIdx.x * blockDim.x + threadIdx.x;
    if (e >= E + N) return;
    int s, d; edge_sd(ei, E, e, s, d);
    int pos = offsets[d] + atomicAdd(&cursor[d], 1);
    csr_src[pos] = s;
}

// Fused: deg histogram (block's threads cover edge range) + xl1 = x@W1 (fp16 out)
// + es1/ed1 attention scores. Block = 256 thr; wave = head; grid = N blocks.
__global__ void xw1_attn(const float* __restrict__ x, const float* __restrict__ W1,
                         const float* __restrict__ a_src, const float* __restrict__ a_dst,
                         const int* __restrict__ ei, int E, int ET, int* __restrict__ deg,
                         __half2* __restrict__ xlh, float* __restrict__ es, float* __restrict__ ed,
                         int n) {
    int ge = blockIdx.x * 256 + threadIdx.x;
    if (ge < ET) {
        int s, d; edge_sd(ei, E, ge, s, d);
        atomicAdd(&deg[d], 1);
    }
    int node = blockIdx.x;
    int t = threadIdx.x;
    __shared__ float xs[6];
    if (t < 6) xs[t] = x[node * 6 + t];
    __syncthreads();
    int j0 = 2 * t, j1 = 2 * t + 1;
    float v0 = 0.f, v1 = 0.f;
#pragma unroll
    for (int k = 0; k < 6; ++k) {
        v0 += xs[k] * W1[k * 512 + j0];
        v1 += xs[k] * W1[k * 512 + j1];
    }
    xlh[(size_t)node * 256 + t] = __floats2half2_rn(v0, v1);
    float ps = v0 * a_src[j0] + v1 * a_src[j1];
    float pd = v0 * a_dst[j0] + v1 * a_dst[j1];
#pragma unroll
    for (int off = 32; off; off >>= 1) {
        ps += __shfl_xor(ps, off);
        pd += __shfl_xor(pd, off);
    }
    int h = t >> 6, lane = t & 63;
    if (lane == 0) { es[node * 4 + h] = ps; ed[node * 4 + h] = pd; }
}

// GAT1 aggregation, ALL 4 HEADS per wave (wave = node, 4 nodes / 256-thr block),
// with INLINE softmax weights: staging gathers es[s] (float4), computes
// a=exp(leaky(es+ed)) per head, accumulates lane-local denom; one 64-lane reduce
// per node at the end. No alpha/dinv buffers. Each edge = ONE 1KB contiguous
// wave gather of the 512-ch fp16 row; fp16 natural-order 1KB contiguous store.
__global__ void agg4_kernel(const __half* __restrict__ xlh, const float* __restrict__ es,
                            const float* __restrict__ ed, const int* __restrict__ offsets,
                            const int* __restrict__ csr_src, const float* __restrict__ bias,
                            __half* __restrict__ outh, int n) {
    __shared__ int   s_src[4 * 64];
    __shared__ float s_al [4 * 64 * 4];
    int t = threadIdx.x, wave = t >> 6, lane = t & 63;
    int node = blockIdx.x * 4 + wave;
    int beg = offsets[node], end = offsets[node + 1];
    int woff = wave * 64;
    int hsel = lane >> 4;                 // head of channels 8l..8l+7
    float4 edv4 = *(const float4*)(ed + (size_t)node * 4);
    float dn0 = 0.f, dn1 = 0.f, dn2 = 0.f, dn3 = 0.f;
    float acc[8] = {0.f, 0.f, 0.f, 0.f, 0.f, 0.f, 0.f, 0.f};

    auto accum = [&](float4 r, float a) {
        const __half2* hp = (const __half2*)&r;
        float2 f0 = __half22float2(hp[0]), f1 = __half22float2(hp[1]);
        float2 f2 = __half22float2(hp[2]), f3 = __half22float2(hp[3]);
        acc[0] += a * f0.x; acc[1] += a * f0.y;
        acc[2] += a * f1.x; acc[3] += a * f1.y;
        acc[4] += a * f2.x; acc[5] += a * f2.y;
        acc[6] += a * f3.x; acc[7] += a * f3.y;
    };

    for (int chunk = beg; chunk < end; chunk += 64) {
        int i = chunk + lane;
        bool valid = i < end;
        int s = valid ? csr_src[i] : 0;
        s_src[woff + lane] = s;
        float4 a4 = make_float4(0.f, 0.f, 0.f, 0.f);
        if (valid) {
            float4 e4 = *(const float4*)(es + (size_t)s * 4);
            float wv;
            wv = e4.x + edv4.x; wv = (wv > 0.f) ? wv : NEG_SLOPE * wv; a4.x = __expf(wv);
            wv = e4.y + edv4.y; wv = (wv > 0.f) ? wv : NEG_SLOPE * wv; a4.y = __expf(wv);
            wv = e4.z + edv4.z; wv = (wv > 0.f) ? wv : NEG_SLOPE * wv; a4.z = __expf(wv);
            wv = e4.w + edv4.w; wv = (wv > 0.f) ? wv : NEG_SLOPE * wv; a4.w = __expf(wv);
        }
        *(float4*)&s_al[(woff + lane) * 4] = a4;
        dn0 += a4.x; dn1 += a4.y; dn2 += a4.z; dn3 += a4.w;
        int cnt = end - chunk; if (cnt > 64) cnt = 64;
        int base = 0;
        for (; base + 8 <= cnt; base += 8) {
            int s0 = s_src[woff+base+0], s1 = s_src[woff+base+1];
            int s2 = s_src[woff+base+2], s3 = s_src[woff+base+3];
            int s4 = s_src[woff+base+4], s5 = s_src[woff+base+5];
            int s6 = s_src[woff+base+6], s7 = s_src[woff+base+7];
            float a0 = s_al[(woff+base+0)*4 + hsel], a1 = s_al[(woff+base+1)*4 + hsel];
            float a2 = s_al[(woff+base+2)*4 + hsel], a3 = s_al[(woff+base+3)*4 + hsel];
            float a4v = s_al[(woff+base+4)*4 + hsel], a5 = s_al[(woff+base+5)*4 + hsel];
            float a6 = s_al[(woff+base+6)*4 + hsel], a7 = s_al[(woff+base+7)*4 + hsel];
            float4 r0 = *(const float4*)(xlh + (size_t)s0 * 512 + lane * 8);
            float4 r1 = *(const float4*)(xlh + (size_t)s1 * 512 + lane * 8);
            float4 r2 = *(const float4*)(xlh + (size_t)s2 * 512 + lane * 8);
            float4 r3 = *(const float4*)(xlh + (size_t)s3 * 512 + lane * 8);
            float4 r4 = *(const float4*)(xlh + (size_t)s4 * 512 + lane * 8);
            float4 r5 = *(const float4*)(xlh + (size_t)s5 * 512 + lane * 8);
            float4 r6 = *(const float4*)(xlh + (size_t)s6 * 512 + lane * 8);
            float4 r7 = *(const float4*)(xlh + (size_t)s7 * 512 + lane * 8);
            accum(r0, a0); accum(r1, a1); accum(r2, a2); accum(r3, a3);
            accum(r4, a4v); accum(r5, a5); accum(r6, a6); accum(r7, a7);
        }
        for (; base < cnt; ++base) {
            int   sv = s_src[woff + base];
            float av1 = s_al[(woff + base) * 4 + hsel];
            float4 r = *(const float4*)(xlh + (size_t)sv * 512 + lane * 8);
            accum(r, av1);
        }
    }
#pragma unroll
    for (int off = 32; off; off >>= 1) {
        dn0 += __shfl_xor(dn0, off);
        dn1 += __shfl_xor(dn1, off);
        dn2 += __shfl_xor(dn2, off);
        dn3 += __shfl_xor(dn3, off);
    }
    float dsel = (hsel == 0) ? dn0 : (hsel == 1) ? dn1 : (hsel == 2) ? dn2 : dn3;
    float inv = 1.f / dsel;
    int c0 = lane * 8;
    float o[8];
#pragma unroll
    for (int k = 0; k < 8; ++k) o[k] = fmaxf(acc[k] * inv + bias[c0 + k], 0.f);
    float4 pack;
    ((__half2*)&pack)[0] = __floats2half2_rn(o[0], o[1]);
    ((__half2*)&pack)[1] = __floats2half2_rn(o[2], o[3]);
    ((__half2*)&pack)[2] = __floats2half2_rn(o[4], o[5]);
    ((__half2*)&pack)[3] = __floats2half2_rn(o[6], o[7]);
    *(float4*)(outh + (size_t)node * 512 + lane * 8) = pack;
}

// xl2 = h @ W2 via MFMA f16: [10000x512]@[512x128]. 625 blocks x 256 thr (4 waves).
__global__ void __launch_bounds__(256)
xw2_mfma(const __half* __restrict__ h16, const __half* __restrict__ W2t,
         const float* __restrict__ a_src2, const float* __restrict__ a_dst2,
         __half* __restrict__ xl2h, float* __restrict__ es2, float* __restrict__ ed2, int n) {
    __shared__ float xs[16][132];     // [row][col], +4 pad
    int t = threadIdx.x, w = t >> 6, l = t & 63;
    int m0 = blockIdx.x * 16;
    int rc = l & 15, kg = l >> 4;
    f32x4 acc0 = {0.f, 0.f, 0.f, 0.f}, acc1 = {0.f, 0.f, 0.f, 0.f};
    const __half* arow = h16 + (size_t)(m0 + rc) * 512 + kg * 8;
    const __half* b0p  = W2t + (size_t)(w * 32 + rc) * 512 + kg * 8;
    const __half* b1p  = W2t + (size_t)(w * 32 + 16 + rc) * 512 + kg * 8;
    for (int ks = 0; ks < 512; ks += 32) {
        f16x8 a  = *(const f16x8*)(arow + ks);
        f16x8 b0 = *(const f16x8*)(b0p + ks);
        f16x8 b1 = *(const f16x8*)(b1p + ks);
        acc0 = __builtin_amdgcn_mfma_f32_16x16x32_f16(a, b0, acc0, 0, 0, 0);
        acc1 = __builtin_amdgcn_mfma_f32_16x16x32_f16(a, b1, acc1, 0, 0, 0);
    }
#pragma unroll
    for (int i = 0; i < 4; ++i) {
        xs[kg * 4 + i][w * 32 + rc]      = acc0[i];
        xs[kg * 4 + i][w * 32 + 16 + rc] = acc1[i];
    }
    __syncthreads();
    int r = t >> 4, c0 = (t & 15) * 8;
    float v[8];
#pragma unroll
    for (int j = 0; j < 8; ++j) v[j] = xs[r][c0 + j];
    float4 pack;
    ((__half2*)&pack)[0] = __floats2half2_rn(v[0], v[1]);
    ((__half2*)&pack)[1] = __floats2half2_rn(v[2], v[3]);
    ((__half2*)&pack)[2] = __floats2half2_rn(v[4], v[5]);
    ((__half2*)&pack)[3] = __floats2half2_rn(v[6], v[7]);
    *(float4*)(xl2h + (size_t)(m0 + r) * 128 + c0) = pack;
    float ps = 0.f, pd = 0.f;
#pragma unroll
    for (int j = 0; j < 8; ++j) {
        ps += v[j] * a_src2[c0 + j];
        pd += v[j] * a_dst2[c0 + j];
    }
#pragma unroll
    for (int off = 8; off; off >>= 1) {
        ps += __shfl_xor(ps, off);
        pd += __shfl_xor(pd, off);
    }
    if ((l & 15) == 0) { es2[m0 + r] = ps; ed2[m0 + r] = pd; }
}

// GAT2 weighted gather (H=1) with INLINE softmax weights (es2 gather + exp in
// staging, lane-local denom, one wave reduce). Wide-load 4-edges/instr; LDS
// redistribute epilogue; contiguous float2 stores to h2. No atomics.
__global__ void agg1_kernel(const __half* __restrict__ xlh, const float* __restrict__ es,
                            const float* __restrict__ ed, const int* __restrict__ offsets,
                            const int* __restrict__ csr_src, const float* __restrict__ bias,
                            float* __restrict__ h2, int n) {
    __shared__ int   s_src[4 * 64];
    __shared__ float s_al [4 * 64];
    __shared__ float s_red[4][64][8];
    int t = threadIdx.x, wave = t >> 6, lane = t & 63;
    int node = blockIdx.x * 4 + wave;
    int beg = offsets[node], end = offsets[node + 1];
    int woff = wave * 64;
    int lg = lane >> 4;
    int lc = lane & 15;
    float edv = ed[node];
    float dn = 0.f;
    float acc[8] = {0.f, 0.f, 0.f, 0.f, 0.f, 0.f, 0.f, 0.f};

    auto accum = [&](float4 r, float a) {
        const __half2* hp = (const __half2*)&r;
        float2 f0 = __half22float2(hp[0]), f1 = __half22float2(hp[1]);
        float2 f2 = __half22float2(hp[2]), f3 = __half22float2(hp[3]);
        acc[0] += a * f0.x; acc[1] += a * f0.y;
        acc[2] += a * f1.x; acc[3] += a * f1.y;
        acc[4] += a * f2.x; acc[5] += a * f2.y;
        acc[6] += a * f3.x; acc[7] += a * f3.y;
    };

    for (int chunk = beg; chunk < end; chunk += 64) {
        int i = chunk + lane;
        bool valid = i < end;
        int s = valid ? csr_src[i] : 0;
        s_src[woff + lane] = s;
        float a = 0.f;
        if (valid) {
            float wv = es[s] + edv;
            wv = (wv > 0.f) ? wv : NEG_SLOPE * wv;
            a = __expf(wv);
        }
        s_al[woff + lane] = a;
        dn += a;
        int cnt = end - chunk; if (cnt > 64) cnt = 64;
        int base = 0;
        for (; base + 16 <= cnt; base += 16) {
            int e0 = base + lg, e1 = base + 4 + lg, e2 = base + 8 + lg, e3 = base + 12 + lg;
            int   s0 = s_src[woff + e0], s1 = s_src[woff + e1];
            int   s2 = s_src[woff + e2], s3 = s_src[woff + e3];
            float a0 = s_al[woff + e0], a1 = s_al[woff + e1];
            float a2 = s_al[woff + e2], a3 = s_al[woff + e3];
            float4 r0 = *(const float4*)(xlh + (size_t)s0 * 128 + lc * 8);
            float4 r1 = *(const float4*)(xlh + (size_t)s1 * 128 + lc * 8);
            float4 r2 = *(const float4*)(xlh + (size_t)s2 * 128 + lc * 8);
            float4 r3 = *(const float4*)(xlh + (size_t)s3 * 128 + lc * 8);
            accum(r0, a0); accum(r1, a1); accum(r2, a2); accum(r3, a3);
        }
        for (; base < cnt; base += 4) {
            int eg = base + lg;
            bool v = eg < cnt;
            int   sv = v ? s_src[woff + eg] : 0;
            float av = v ? s_al[woff + eg] : 0.f;
            float4 r = *(const float4*)(xlh + (size_t)sv * 128 + lc * 8);
            accum(r, av);
        }
    }
#pragma unroll
    for (int off = 32; off; off >>= 1) dn += __shfl_xor(dn, off);
    float4* dst = (float4*)&s_red[wave][lane][0];
    dst[0] = make_float4(acc[0], acc[1], acc[2], acc[3]);
    dst[1] = make_float4(acc[4], acc[5], acc[6], acc[7]);
    int lcs = lane >> 2;
    int pe  = lane & 3;
    float vx = 0.f, vy = 0.f;
#pragma unroll
    for (int g = 0; g < 4; ++g) {
        float2 p = ((float2*)&s_red[wave][g * 16 + lcs][0])[pe];
        vx += p.x; vy += p.y;
    }
    float inv = 1.f / dn;
    int j0 = 2 * lane;
    float o0 = fmaxf(vx * inv + bias[j0], 0.f);
    float o1 = fmaxf(vy * inv + bias[j0 + 1], 0.f);
    float2* op = (float2*)(h2 + (size_t)node * 128);
    op[lane] = make_float2(o0, o1);
}

__device__ __forceinline__ int lower_bound_i(const int* a, int n, int key) {
    int lo = 0, hi = n;
    while (lo < hi) {
        int mid = (lo + hi) >> 1;
        if (a[mid] < key) lo = mid + 1; else hi = mid;
    }
    return lo;
}

// Fused mean-pool + MLP head. One block (512 thr) per graph; batch SORTED ->
// contiguous node range by binary search. No atomics.
__global__ void __launch_bounds__(512)
pool_mlp_kernel(const float* __restrict__ h2, const int* __restrict__ batch,
                const float* __restrict__ mw1, const float* __restrict__ mb1,
                const float* __restrict__ mw2, const float* __restrict__ mb2,
                float* __restrict__ out, int n) {
    __shared__ float part[4][128];
    __shared__ float gm[128], tbuf[128];
    int g = blockIdx.x, t = threadIdx.x;
    int j = t & 127, rg = t >> 7;
    int a = lower_bound_i(batch, n, g);
    int b = lower_bound_i(batch, n, g + 1);
    float s = 0.f;
    for (int i = a + rg; i < b; i += 4) s += h2[(size_t)i * 128 + j];
    part[rg][j] = s;
    __syncthreads();
    if (t < 128) {
        float cnt = fmaxf((float)(b - a), 1.f);
        gm[j] = (part[0][j] + part[1][j] + part[2][j] + part[3][j]) / cnt;
    }
    __syncthreads();
    if (t < 128) {
        float v = mb1[j];
        for (int k = 0; k < 128; ++k) v += gm[k] * mw1[k * 128 + j];
        tbuf[j] = fmaxf(v, 0.f);
    }
    __syncthreads();
    if (t < 4) {
        float o = mb2[t];
        for (int k = 0; k < 128; ++k) o += tbuf[k] * mw2[k * 4 + t];
        out[g * 4 + t] = o;
    }
}

extern "C" void kernel_launch(void* const* d_in, const int* in_sizes, int n_in,
                              void* d_out, int out_size, void* d_ws, size_t ws_size,
                              hipStream_t stream) {
    const float* x       = (const float*)d_in[0];
    const int*   ei      = (const int*)d_in[1];
    const int*   batch   = (const int*)d_in[2];
    const float* W1      = (const float*)d_in[3];
    const float* a_src1  = (const float*)d_in[4];
    const float* a_dst1  = (const float*)d_in[5];
    const float* b1      = (const float*)d_in[6];
    const float* W2      = (const float*)d_in[7];
    const float* a_src2  = (const float*)d_in[8];
    const float* a_dst2  = (const float*)d_in[9];
    const float* b2      = (const float*)d_in[10];
    const float* mw1     = (const float*)d_in[11];
    const float* mb1     = (const float*)d_in[12];
    const float* mw2     = (const float*)d_in[13];
    const float* mb2     = (const float*)d_in[14];
    float* out = (float*)d_out;

    const int N = in_sizes[0] / 6;      // 10000
    const int E = in_sizes[1] / 2;      // 160000
    const int ET = E + N;               // with self-loops
    const int G = 64;

    char* ws = (char*)d_ws;
    size_t off = 0;
    auto alloc = [&](size_t bytes) {
        void* p = ws + off;
        off += (bytes + 15) & ~(size_t)15;
        return p;
    };
    __half* xl1h   = (__half*)alloc((size_t)N * 512 * 2);
    __half* hbufh  = (__half*)alloc((size_t)N * 512 * 2);
    __half* xl2h   = (__half*)alloc((size_t)N * 128 * 2);
    float*  h2     = (float*)alloc((size_t)N * 128 * 4);
    __half* W2t    = (__half*)alloc((size_t)512 * 128 * 2);
    float*  es1    = (float*)alloc((size_t)N * 4 * 4);
    float*  ed1    = (float*)alloc((size_t)N * 4 * 4);
    float*  es2    = (float*)alloc((size_t)N * 4);
    float*  ed2    = (float*)alloc((size_t)N * 4);
    int*    offsets= (int*)alloc((size_t)(N + 1) * 4);
    int*    zbase  = (int*)alloc((size_t)N * 4 + (size_t)N * 4);
    int*    deg    = zbase;
    int*    cursor = zbase + N;
    int*    csr_src= (int*)alloc((size_t)ET * 4);
    (void)ws_size; (void)n_in; (void)out_size;

    const int zn = 2 * N;
    const int setup_n = 65536 + zn;

    setup_kernel<<<(setup_n + 255) / 256, 256, 0, stream>>>(W2, W2t, zbase, zn);
    xw1_attn<<<N, 256, 0, stream>>>(x, W1, a_src1, a_dst1, ei, E, ET, deg,
                                    (__half2*)xl1h, es1, ed1, N);
    scan_kernel<<<1, 1024, 0, stream>>>(deg, offsets, N);
    fill_kernel<<<(ET + 255) / 256, 256, 0, stream>>>(ei, E, N, offsets, cursor, csr_src);
    agg4_kernel<<<N / 4, 256, 0, stream>>>(xl1h, es1, ed1, offsets, csr_src, b1, hbufh, N);
    xw2_mfma<<<N / 16, 256, 0, stream>>>(hbufh, W2t, a_src2, a_dst2, xl2h, es2, ed2, N);
    agg1_kernel<<<N / 4, 256, 0, stream>>>(xl2h, es2, ed2, offsets, csr_src, b2, h2, N);
    pool_mlp_kernel<<<G, 512, 0, stream>>>(h2, batch, mw1, mb1, mw2, mb2, out, N);
}